// Round 1
// baseline (520.214 us; speedup 1.0000x reference)
//
#include <hip/hip_runtime.h>
#include <cstdint>
#include <cstddef>

#define NN 8192
#define FIN 256
#define HH 64

typedef float vf4 __attribute__((ext_vector_type(4)));
typedef short vbf8 __attribute__((ext_vector_type(8)));

// pack two fp32 -> two bf16 (truncation) in one v_perm
__device__ inline unsigned pk_trunc(float lo, float hi) {
  return __builtin_amdgcn_perm(__float_as_uint(hi), __float_as_uint(lo), 0x07060302u);
}
__device__ inline unsigned short bf_rne(float x) {
  unsigned u = __float_as_uint(x);
  return (unsigned short)((u + 0x7FFFu + ((u >> 16) & 1u)) >> 16);
}
__device__ inline float bf_to_f(unsigned short s) {
  return __uint_as_float(((unsigned)s) << 16);
}

union FragU { unsigned u[4]; unsigned short s[8]; vbf8 v; };

__device__ inline vbf8 frag_trunc(vf4 a, vf4 b) {
  FragU t;
  t.u[0] = pk_trunc(a[0], a[1]);
  t.u[1] = pk_trunc(a[2], a[3]);
  t.u[2] = pk_trunc(b[0], b[1]);
  t.u[3] = pk_trunc(b[2], b[3]);
  return t.v;
}
__device__ inline vbf8 frag_rne(vf4 a, vf4 b) {
  FragU t;
  t.s[0] = bf_rne(a[0]); t.s[1] = bf_rne(a[1]); t.s[2] = bf_rne(a[2]); t.s[3] = bf_rne(a[3]);
  t.s[4] = bf_rne(b[0]); t.s[5] = bf_rne(b[1]); t.s[6] = bf_rne(b[2]); t.s[7] = bf_rne(b[3]);
  return t.v;
}

// ---------------- k1: fts = seq @ fc_w^T (both seqs), write Bt[n][k] bf16 -----
// Wave = 16 rows x 64 h, K=256. MFMA 16x16x32 bf16.
// A frag: seq[m0+ (lane&15)][k + (lane>>4)*8 + j] (8 contiguous fp32/lane)
// B frag: fc_w[16f + (lane&15)][k + (lane>>4)*8 + j]  (fc_w row-major == B^T)
// C/D: col(n)=lane&15, row(m)=(lane>>4)*4+reg  [m89/m91 verified]
__global__ __launch_bounds__(256) void k1_fts(
    const float* __restrict__ seq1, const float* __restrict__ seq2,
    const float* __restrict__ fcw, unsigned short* __restrict__ Bt,
    float* __restrict__ csum) {
  const int bx = blockIdx.x;           // 256 blocks
  const int s = bx & 1, mb = bx >> 1;  // seq select, m-block 0..127
  const int wave = threadIdx.x >> 6, lane = threadIdx.x & 63;
  const int r = lane & 15, q = lane >> 4;
  const int m0 = mb * 64 + wave * 16;
  if (bx == 0 && threadIdx.x < 64) csum[threadIdx.x] = 0.f;  // zero accumulator for k3
  const float* seq = s ? seq2 : seq1;
  const float* ap = seq + (size_t)(m0 + r) * FIN + q * 8;
  const float* bp = fcw + (size_t)r * FIN + q * 8;
  vf4 acc[4] = {};
#pragma unroll
  for (int kk = 0; kk < FIN; kk += 32) {
    vf4 a0 = *(const vf4*)ap;
    vf4 a1 = *(const vf4*)(ap + 4);
    vbf8 af = frag_rne(a0, a1);
#pragma unroll
    for (int f = 0; f < 4; ++f) {
      vf4 b0 = *(const vf4*)(bp + (size_t)f * 16 * FIN);
      vf4 b1 = *(const vf4*)(bp + (size_t)f * 16 * FIN + 4);
      vbf8 bfr = frag_rne(b0, b1);
      acc[f] = __builtin_amdgcn_mfma_f32_16x16x32_bf16(af, bfr, acc[f], 0, 0, 0);
    }
    ap += 32; bp += 32;
  }
  // write transposed: Bt[h_global][m], 4 consecutive m per lane -> 8B store
#pragma unroll
  for (int f = 0; f < 4; ++f) {
    short4 v;
    v.x = (short)bf_rne(acc[f][0]);
    v.y = (short)bf_rne(acc[f][1]);
    v.z = (short)bf_rne(acc[f][2]);
    v.w = (short)bf_rne(acc[f][3]);
    unsigned short* dst = Bt + (size_t)(64 * s + 16 * f + r) * NN + m0 + q * 4;
    *(short4*)dst = v;
  }
}

// ---------------- k2: Cpart[slice] = adj[:, kslice] @ B[kslice, :]  ----------
// Wave: 16 rows x 128 cols, K-slice 2048, 64 K-steps of 32.
// No LDS/barriers: A fp32 streamed (nontemporal) + trunc->bf16; B frags direct
// from L2-resident Bt (16 rows x 64B full-line footprint per load).
__global__ __launch_bounds__(256, 2) void k2_agg(
    const float* __restrict__ adj, const unsigned short* __restrict__ Bt,
    unsigned short* __restrict__ Cpart) {
  const int bx = blockIdx.x;             // 512 blocks
  const int slice = bx & 3, mb = bx >> 2;
  const int wave = threadIdx.x >> 6, lane = threadIdx.x & 63;
  const int r = lane & 15, q = lane >> 4;
  const int m0 = mb * 64 + wave * 16;
  const int k0 = slice * 2048;
  const vf4* ap = (const vf4*)(adj + (size_t)(m0 + r) * NN + k0 + q * 8);
  const unsigned short* bp = Bt + (size_t)r * NN + k0 + q * 8;
  vf4 acc[8] = {};
#pragma unroll 4
  for (int it = 0; it < 64; ++it) {
    vf4 a0 = __builtin_nontemporal_load(ap);
    vf4 a1 = __builtin_nontemporal_load(ap + 1);
    vbf8 af = frag_trunc(a0, a1);
#pragma unroll
    for (int f = 0; f < 8; ++f) {
      vbf8 bfr = *(const vbf8*)(bp + (size_t)f * 16 * NN);
      acc[f] = __builtin_amdgcn_mfma_f32_16x16x32_bf16(af, bfr, acc[f], 0, 0, 0);
    }
    ap += 8; bp += 32;
  }
  // store bf16 partials: Cpart[slice][m][n]
  unsigned short* cp = Cpart + ((size_t)slice * NN + m0 + q * 4) * 128 + r;
#pragma unroll
  for (int f = 0; f < 8; ++f)
#pragma unroll
    for (int reg = 0; reg < 4; ++reg)
      cp[(size_t)reg * 128 + f * 16] = bf_rne(acc[f][reg]);
}

// ---------------- k3: csum[h] += sum_m PReLU(sum_s Cpart + bias) * msk -------
__global__ __launch_bounds__(256) void k3_csum(
    const unsigned short* __restrict__ Cpart, const float* __restrict__ bias,
    const float* __restrict__ alpha_p, const float* __restrict__ msk,
    float* __restrict__ csum) {
  const int t = threadIdx.x, h = t & 63, r0 = t >> 6;
  const int m0 = blockIdx.x * 64;  // 128 blocks
  const float alpha = alpha_p[0], b = bias[h];
  float sum = 0.f;
  for (int i = 0; i < 16; ++i) {
    const int m = m0 + r0 * 16 + i;
    float v = 0.f;
#pragma unroll
    for (int s = 0; s < 4; ++s) v += bf_to_f(Cpart[((size_t)s * NN + m) * 128 + h]);
    v += b;
    v = v > 0.f ? v : alpha * v;
    sum += v * msk[m];
  }
  __shared__ float red[256];
  red[t] = sum;
  __syncthreads();
  if (t < 64) atomicAdd(&csum[h], red[t] + red[t + 64] + red[t + 128] + red[t + 192]);
}

// ---------------- k4: c=sigmoid(csum/Σmsk); wc=disc_w@c; sc = h·wc + b -------
__global__ __launch_bounds__(256) void k4_sc(
    const unsigned short* __restrict__ Cpart, const float* __restrict__ bias,
    const float* __restrict__ alpha_p, const float* __restrict__ msk,
    const float* __restrict__ csum, const float* __restrict__ discw,
    const float* __restrict__ discb, float* __restrict__ out) {
  const int t = threadIdx.x;
  __shared__ float red[256];
  __shared__ float c_sh[64], wc_sh[64];
  float ms = 0.f;
  for (int i = 0; i < 32; ++i) ms += msk[t + 256 * i];
  red[t] = ms;
  __syncthreads();
  for (int off = 128; off > 0; off >>= 1) {
    if (t < off) red[t] += red[t + off];
    __syncthreads();
  }
  const float msksum = red[0];
  if (t < 64) c_sh[t] = 1.f / (1.f + __expf(-csum[t] / msksum));
  __syncthreads();
  if (t < 64) {
    float w = 0.f;
    for (int k = 0; k < 64; ++k) w += discw[t * 64 + k] * c_sh[k];
    wc_sh[t] = w;
  }
  __syncthreads();
  const int lane = t & 63, wave = t >> 6;
  const float alpha = alpha_p[0], b = bias[lane], w = wc_sh[lane], db = discb[0];
  const int m0 = blockIdx.x * 64;  // 128 blocks
  for (int i = 0; i < 16; ++i) {
    const int m = m0 + wave * 16 + i;
    float v1 = 0.f, v2 = 0.f;
#pragma unroll
    for (int s = 0; s < 4; ++s) {
      v1 += bf_to_f(Cpart[((size_t)s * NN + m) * 128 + lane]);
      v2 += bf_to_f(Cpart[((size_t)s * NN + m) * 128 + 64 + lane]);
    }
    v1 += b; v1 = v1 > 0.f ? v1 : alpha * v1; v1 *= w;
    v2 += b; v2 = v2 > 0.f ? v2 : alpha * v2; v2 *= w;
#pragma unroll
    for (int off = 32; off > 0; off >>= 1) {
      v1 += __shfl_down(v1, off);
      v2 += __shfl_down(v2, off);
    }
    if (lane == 0) { out[m] = v1 + db; out[NN + m] = v2 + db; }
  }
}

extern "C" void kernel_launch(void* const* d_in, const int* in_sizes, int n_in,
                              void* d_out, int out_size, void* d_ws, size_t ws_size,
                              hipStream_t stream) {
  const float* seq1  = (const float*)d_in[0];
  const float* seq2  = (const float*)d_in[1];
  const float* adj   = (const float*)d_in[2];
  const float* msk   = (const float*)d_in[3];
  const float* fcw   = (const float*)d_in[4];
  const float* bias  = (const float*)d_in[5];
  const float* alpha = (const float*)d_in[6];
  const float* discw = (const float*)d_in[7];
  const float* discb = (const float*)d_in[8];
  float* out = (float*)d_out;

  char* ws = (char*)d_ws;
  unsigned short* Bt    = (unsigned short*)ws;                          // 2 MB  [128][8192] bf16
  unsigned short* Cpart = (unsigned short*)(ws + (size_t)(2 << 20));    // 8 MB  [4][8192][128] bf16
  float* csum           = (float*)(ws + (size_t)(10 << 20));            // 64 fp32

  hipLaunchKernelGGL(k1_fts, dim3(256), dim3(256), 0, stream, seq1, seq2, fcw, Bt, csum);
  hipLaunchKernelGGL(k2_agg, dim3(512), dim3(256), 0, stream, adj, Bt, Cpart);
  hipLaunchKernelGGL(k3_csum, dim3(128), dim3(256), 0, stream, Cpart, bias, alpha, msk, csum);
  hipLaunchKernelGGL(k4_sc, dim3(128), dim3(256), 0, stream, Cpart, bias, alpha, msk, csum,
                     discw, discb, out);
}

// Round 2
// 505.805 us; speedup vs baseline: 1.0285x; 1.0285x over previous
//
#include <hip/hip_runtime.h>
#include <cstdint>
#include <cstddef>

#define NN 8192
#define FIN 256
#define HH 64

typedef float vf4 __attribute__((ext_vector_type(4)));
typedef short vbf8 __attribute__((ext_vector_type(8)));

__device__ inline unsigned pk_trunc(float lo, float hi) {
  return __builtin_amdgcn_perm(__float_as_uint(hi), __float_as_uint(lo), 0x07060302u);
}
__device__ inline unsigned short bf_rne(float x) {
  unsigned u = __float_as_uint(x);
  return (unsigned short)((u + 0x7FFFu + ((u >> 16) & 1u)) >> 16);
}
__device__ inline float bf_to_f(unsigned short s) {
  return __uint_as_float(((unsigned)s) << 16);
}

union FragU { unsigned u[4]; unsigned short s[8]; vbf8 v; };

__device__ inline vbf8 frag_trunc(vf4 a, vf4 b) {
  FragU t;
  t.u[0] = pk_trunc(a[0], a[1]);
  t.u[1] = pk_trunc(a[2], a[3]);
  t.u[2] = pk_trunc(b[0], b[1]);
  t.u[3] = pk_trunc(b[2], b[3]);
  return t.v;
}
__device__ inline vbf8 frag_rne(vf4 a, vf4 b) {
  FragU t;
  t.s[0] = bf_rne(a[0]); t.s[1] = bf_rne(a[1]); t.s[2] = bf_rne(a[2]); t.s[3] = bf_rne(a[3]);
  t.s[4] = bf_rne(b[0]); t.s[5] = bf_rne(b[1]); t.s[6] = bf_rne(b[2]); t.s[7] = bf_rne(b[3]);
  return t.v;
}

// ---------------- k1: fts = seq @ fc_w^T (both seqs), write Bt[n][k] bf16 -----
__global__ __launch_bounds__(256) void k1_fts(
    const float* __restrict__ seq1, const float* __restrict__ seq2,
    const float* __restrict__ fcw, unsigned short* __restrict__ Bt,
    float* __restrict__ csum) {
  const int bx = blockIdx.x;           // 256 blocks
  const int s = bx & 1, mb = bx >> 1;
  const int wave = threadIdx.x >> 6, lane = threadIdx.x & 63;
  const int r = lane & 15, q = lane >> 4;
  const int m0 = mb * 64 + wave * 16;
  if (bx == 0 && threadIdx.x < 64) csum[threadIdx.x] = 0.f;
  const float* seq = s ? seq2 : seq1;
  const float* ap = seq + (size_t)(m0 + r) * FIN + q * 8;
  const float* bp = fcw + (size_t)r * FIN + q * 8;
  vf4 acc[4] = {};
#pragma unroll
  for (int kk = 0; kk < FIN; kk += 32) {
    vf4 a0 = *(const vf4*)ap;
    vf4 a1 = *(const vf4*)(ap + 4);
    vbf8 af = frag_rne(a0, a1);
#pragma unroll
    for (int f = 0; f < 4; ++f) {
      vf4 b0 = *(const vf4*)(bp + (size_t)f * 16 * FIN);
      vf4 b1 = *(const vf4*)(bp + (size_t)f * 16 * FIN + 4);
      vbf8 bfr = frag_rne(b0, b1);
      acc[f] = __builtin_amdgcn_mfma_f32_16x16x32_bf16(af, bfr, acc[f], 0, 0, 0);
    }
    ap += 32; bp += 32;
  }
#pragma unroll
  for (int f = 0; f < 4; ++f) {
    short4 v;
    v.x = (short)bf_rne(acc[f][0]);
    v.y = (short)bf_rne(acc[f][1]);
    v.z = (short)bf_rne(acc[f][2]);
    v.w = (short)bf_rne(acc[f][3]);
    unsigned short* dst = Bt + (size_t)(64 * s + 16 * f + r) * NN + m0 + q * 4;
    *(short4*)dst = v;
  }
}

// ---------------- k2: Cpart[slice][n][m] = (adj[:, kslice] @ B[kslice, :])^T --
// grid 128*SPLIT blocks x 256 thr -> 512*SPLIT waves. SPLIT=16: 32 waves/CU.
template <int SPLIT>
__global__ __launch_bounds__(256, 8) void k2_agg(
    const float* __restrict__ adj, const unsigned short* __restrict__ Bt,
    unsigned short* __restrict__ Cpart) {
  const int KLEN = NN / SPLIT;
  const int bx = blockIdx.x;
  const int slice = bx % SPLIT, mb = bx / SPLIT;
  const int wave = threadIdx.x >> 6, lane = threadIdx.x & 63;
  const int r = lane & 15, q = lane >> 4;
  const int m0 = mb * 64 + wave * 16;
  const int k0 = slice * KLEN;
  const vf4* ap = (const vf4*)(adj + (size_t)(m0 + r) * NN + k0 + q * 8);
  const unsigned short* bp = Bt + (size_t)r * NN + k0 + q * 8;
  vf4 acc[8] = {};
#pragma unroll 4
  for (int it = 0; it < KLEN / 32; ++it) {
    vf4 a0 = __builtin_nontemporal_load(ap);
    vf4 a1 = __builtin_nontemporal_load(ap + 1);
    vbf8 af = frag_trunc(a0, a1);
#pragma unroll
    for (int f = 0; f < 8; ++f) {
      vbf8 bfr = *(const vbf8*)(bp + (size_t)f * 16 * NN);
      acc[f] = __builtin_amdgcn_mfma_f32_16x16x32_bf16(af, bfr, acc[f], 0, 0, 0);
    }
    ap += 8; bp += 32;
  }
  // C/D layout: col n = f*16 + r, row m = m0 + q*4 + reg -> short4 along m.
  // Cpart layout [slice][n][m]: m-contiguous for k3/k4 coalescing.
#pragma unroll
  for (int f = 0; f < 8; ++f) {
    short4 v;
    v.x = (short)bf_rne(acc[f][0]);
    v.y = (short)bf_rne(acc[f][1]);
    v.z = (short)bf_rne(acc[f][2]);
    v.w = (short)bf_rne(acc[f][3]);
    unsigned short* dst = Cpart + ((size_t)slice * 128 + f * 16 + r) * NN + m0 + q * 4;
    *(short4*)dst = v;
  }
}

// ---------------- k3: csum[h] = sum_m PReLU(sum_s Cpart[s][h][m] + b[h])*msk[m]
template <int SPLIT>
__global__ __launch_bounds__(256) void k3_csum(
    const unsigned short* __restrict__ Cpart, const float* __restrict__ bias,
    const float* __restrict__ alpha_p, const float* __restrict__ msk,
    float* __restrict__ csum) {
  const int h = blockIdx.x >> 2, chunk = blockIdx.x & 3;  // 256 blocks
  const int t = threadIdx.x;
  const float alpha = alpha_p[0], b = bias[h];
  float sum = 0.f;
#pragma unroll
  for (int i = 0; i < 8; ++i) {
    const int m = chunk * 2048 + i * 256 + t;
    float v = 0.f;
#pragma unroll
    for (int s = 0; s < SPLIT; ++s)
      v += bf_to_f(Cpart[((size_t)s * 128 + h) * NN + m]);
    v += b;
    v = v > 0.f ? v : alpha * v;
    sum += v * msk[m];
  }
  __shared__ float red[256];
  red[t] = sum;
  __syncthreads();
  for (int off = 128; off > 32; off >>= 1) {
    if (t < off) red[t] += red[t + off];
    __syncthreads();
  }
  if (t < 32) {
    float v = red[t] + red[t + 32];
#pragma unroll
    for (int off = 16; off > 0; off >>= 1) v += __shfl_down(v, off, 64);
    if (t == 0) atomicAdd(&csum[h], v);
  }
}

// ---------------- k3b: msksum, c = sigmoid(csum/msksum), wc = disc_w @ c -----
__global__ __launch_bounds__(256) void k3b(
    const float* __restrict__ msk, const float* __restrict__ csum,
    const float* __restrict__ discw, float* __restrict__ wc) {
  const int t = threadIdx.x;
  __shared__ float red[256];
  __shared__ float c_sh[64];
  float ms = 0.f;
  for (int i = 0; i < 32; ++i) ms += msk[t + 256 * i];
  red[t] = ms;
  __syncthreads();
  for (int off = 128; off > 0; off >>= 1) {
    if (t < off) red[t] += red[t + off];
    __syncthreads();
  }
  if (t < 64) c_sh[t] = 1.f / (1.f + __expf(-csum[t] / red[0]));
  __syncthreads();
  if (t < 64) {
    float w = 0.f;
#pragma unroll
    for (int k = 0; k < 64; ++k) w += discw[t * 64 + k] * c_sh[k];
    wc[t] = w;
  }
}

// ---------------- k4: sc{1,2}[m] = sum_n PReLU(sum_s C[s][n][m]+b)*wc + db ----
template <int SPLIT>
__global__ __launch_bounds__(256) void k4_sc(
    const unsigned short* __restrict__ Cpart, const float* __restrict__ bias,
    const float* __restrict__ alpha_p, const float* __restrict__ wc,
    const float* __restrict__ discb, float* __restrict__ out) {
  const int t = threadIdx.x;
  const int ml = t & 31, g = t >> 5;             // 8 n-groups of 16
  const int m = blockIdx.x * 32 + ml;            // 256 blocks
  const float alpha = alpha_p[0];
  float sum = 0.f;
#pragma unroll
  for (int j = 0; j < 16; ++j) {
    const int n = g * 16 + j, h = n & 63;
    float v = 0.f;
#pragma unroll
    for (int s = 0; s < SPLIT; ++s)
      v += bf_to_f(Cpart[((size_t)s * 128 + n) * NN + m]);
    v += bias[h];
    v = v > 0.f ? v : alpha * v;
    sum += v * wc[h];
  }
  __shared__ float red[8][32];
  red[g][ml] = sum;
  __syncthreads();
  if (t < 64) {
    const int mm = t & 31, half = t >> 5;
    float r = red[half * 4 + 0][mm] + red[half * 4 + 1][mm] +
              red[half * 4 + 2][mm] + red[half * 4 + 3][mm];
    out[(size_t)half * NN + blockIdx.x * 32 + mm] = r + discb[0];
  }
}

template <int SPLIT>
static void launch_all(const float* seq1, const float* seq2, const float* adj,
                       const float* msk, const float* fcw, const float* bias,
                       const float* alpha, const float* discw, const float* discb,
                       float* out, char* ws, hipStream_t stream) {
  unsigned short* Bt = (unsigned short*)ws;                              // 2 MB
  unsigned short* Cpart = (unsigned short*)(ws + (size_t)(2 << 20));     // SPLIT*2 MB
  float* csum = (float*)(ws + (size_t)(2 + 2 * SPLIT) * (1 << 20));      // 64 f
  float* wc = csum + 64;                                                 // 64 f

  hipLaunchKernelGGL(k1_fts, dim3(256), dim3(256), 0, stream, seq1, seq2, fcw, Bt, csum);
  hipLaunchKernelGGL((k2_agg<SPLIT>), dim3(128 * SPLIT), dim3(256), 0, stream, adj, Bt, Cpart);
  hipLaunchKernelGGL((k3_csum<SPLIT>), dim3(256), dim3(256), 0, stream, Cpart, bias, alpha, msk, csum);
  hipLaunchKernelGGL(k3b, dim3(1), dim3(256), 0, stream, msk, csum, discw, wc);
  hipLaunchKernelGGL((k4_sc<SPLIT>), dim3(256), dim3(256), 0, stream, Cpart, bias, alpha, wc, discb, out);
}

extern "C" void kernel_launch(void* const* d_in, const int* in_sizes, int n_in,
                              void* d_out, int out_size, void* d_ws, size_t ws_size,
                              hipStream_t stream) {
  const float* seq1  = (const float*)d_in[0];
  const float* seq2  = (const float*)d_in[1];
  const float* adj   = (const float*)d_in[2];
  const float* msk   = (const float*)d_in[3];
  const float* fcw   = (const float*)d_in[4];
  const float* bias  = (const float*)d_in[5];
  const float* alpha = (const float*)d_in[6];
  const float* discw = (const float*)d_in[7];
  const float* discb = (const float*)d_in[8];
  float* out = (float*)d_out;
  char* ws = (char*)d_ws;

  // ws_size is constant across calls -> deterministic branch, graph-safe.
  if (ws_size >= (size_t)(2 + 32) * (1 << 20) + 4096)
    launch_all<16>(seq1, seq2, adj, msk, fcw, bias, alpha, discw, discb, out, ws, stream);
  else if (ws_size >= (size_t)(2 + 16) * (1 << 20) + 4096)
    launch_all<8>(seq1, seq2, adj, msk, fcw, bias, alpha, discw, discb, out, ws, stream);
  else
    launch_all<4>(seq1, seq2, adj, msk, fcw, bias, alpha, discw, discb, out, ws, stream);
}

// Round 3
// 420.908 us; speedup vs baseline: 1.2359x; 1.2017x over previous
//
#include <hip/hip_runtime.h>
#include <cstdint>
#include <cstddef>

#define NN 8192
#define FIN 256
#define HH 64
#define SPLIT 16
#define KLEN (NN / SPLIT)   // 512

typedef float vf4 __attribute__((ext_vector_type(4)));
typedef short vbf8 __attribute__((ext_vector_type(8)));

__device__ inline unsigned pk_trunc(float lo, float hi) {
  return __builtin_amdgcn_perm(__float_as_uint(hi), __float_as_uint(lo), 0x07060302u);
}
__device__ inline unsigned short bf_rne(float x) {
  unsigned u = __float_as_uint(x);
  return (unsigned short)((u + 0x7FFFu + ((u >> 16) & 1u)) >> 16);
}
__device__ inline float bf_to_f(unsigned short s) {
  return __uint_as_float(((unsigned)s) << 16);
}

union FragU { unsigned u[4]; unsigned short s[8]; vbf8 v; };

__device__ inline vbf8 frag_trunc(vf4 a, vf4 b) {
  FragU t;
  t.u[0] = pk_trunc(a[0], a[1]);
  t.u[1] = pk_trunc(a[2], a[3]);
  t.u[2] = pk_trunc(b[0], b[1]);
  t.u[3] = pk_trunc(b[2], b[3]);
  return t.v;
}
__device__ inline vbf8 frag_rne(vf4 a, vf4 b) {
  FragU t;
  t.s[0] = bf_rne(a[0]); t.s[1] = bf_rne(a[1]); t.s[2] = bf_rne(a[2]); t.s[3] = bf_rne(a[3]);
  t.s[4] = bf_rne(b[0]); t.s[5] = bf_rne(b[1]); t.s[6] = bf_rne(b[2]); t.s[7] = bf_rne(b[3]);
  return t.v;
}

__device__ inline void gl_lds16(const void* g, void* l) {
  __builtin_amdgcn_global_load_lds(
      (const __attribute__((address_space(1))) void*)g,
      (__attribute__((address_space(3))) void*)l, 16, 0, 0);
}

// ---------------- k1: fts = seq @ fc_w^T (both seqs), write Bt[n][k] bf16 -----
__global__ __launch_bounds__(256) void k1_fts(
    const float* __restrict__ seq1, const float* __restrict__ seq2,
    const float* __restrict__ fcw, unsigned short* __restrict__ Bt,
    float* __restrict__ csum) {
  const int bx = blockIdx.x;           // 256 blocks
  const int s = bx & 1, mb = bx >> 1;
  const int wave = threadIdx.x >> 6, lane = threadIdx.x & 63;
  const int r = lane & 15, q = lane >> 4;
  const int m0 = mb * 64 + wave * 16;
  if (bx == 0 && threadIdx.x < 64) csum[threadIdx.x] = 0.f;
  const float* seq = s ? seq2 : seq1;
  const float* ap = seq + (size_t)(m0 + r) * FIN + q * 8;
  const float* bp = fcw + (size_t)r * FIN + q * 8;
  vf4 acc[4] = {};
#pragma unroll
  for (int kk = 0; kk < FIN; kk += 32) {
    vf4 a0 = *(const vf4*)ap;
    vf4 a1 = *(const vf4*)(ap + 4);
    vbf8 af = frag_rne(a0, a1);
#pragma unroll
    for (int f = 0; f < 4; ++f) {
      vf4 b0 = *(const vf4*)(bp + (size_t)f * 16 * FIN);
      vf4 b1 = *(const vf4*)(bp + (size_t)f * 16 * FIN + 4);
      vbf8 bfr = frag_rne(b0, b1);
      acc[f] = __builtin_amdgcn_mfma_f32_16x16x32_bf16(af, bfr, acc[f], 0, 0, 0);
    }
    ap += 32; bp += 32;
  }
#pragma unroll
  for (int f = 0; f < 4; ++f) {
    short4 v;
    v.x = (short)bf_rne(acc[f][0]);
    v.y = (short)bf_rne(acc[f][1]);
    v.z = (short)bf_rne(acc[f][2]);
    v.w = (short)bf_rne(acc[f][3]);
    unsigned short* dst = Bt + (size_t)(64 * s + 16 * f + r) * NN + m0 + q * 4;
    *(short4*)dst = v;
  }
}

// ---------------- k2: Cpart[slice][n][m] = (adj[:,ks] @ B[ks,:])^T -----------
// Block: 512 thr = 8 waves, each wave 32 m-rows x 128 n. M_B=256.
// B slice staged into LDS in fragment order (global_load_lds w=16), double-
// buffered 2x16 KB chunks of k=64. Each block reads its B slice ONCE (128 KB):
// total Bt traffic 64 MB (was 1 GB direct-from-L2 -> hotspot, Round-2 lesson).
// grid 512 = 2 blocks/CU, 16 waves/CU; launch_bounds(512,4) -> 128-reg cap.
__global__ __launch_bounds__(512, 4) void k2_agg(
    const float* __restrict__ adj, const unsigned short* __restrict__ Bt,
    unsigned short* __restrict__ Cpart) {
  constexpr int CHUNKS = KLEN / 64;  // 8
  __shared__ unsigned short lds[2][8192];  // 2 x 16 KB
  const int bx = blockIdx.x;
  const int slice = bx & (SPLIT - 1), mb = bx / SPLIT;
  const int wave = threadIdx.x >> 6, lane = threadIdx.x & 63;
  const int r = lane & 15, q = lane >> 4;
  const int m0 = mb * 256 + wave * 32;
  const int k0 = slice * KLEN;

  // stage chunk ch of B into lds[b]; granule g (16 B) at lds offset g*16 holds
  // Bt[f*16+r'][k0+ch*64+kk*32+q'*8] where g = kk*512 + f*64 + q'*16 + r'.
  // Compute-side ds_read for frag (kk,f) is then lane-contiguous (lane=q*16+r).
  auto stage = [&](int ch, int b) {
#pragma unroll
    for (int j = 0; j < 2; ++j) {
      const int g = j * 512 + wave * 64 + lane;
      const int r_ = g & 15, q_ = (g >> 4) & 3, f_ = (g >> 6) & 7, kk_ = g >> 9;
      const unsigned short* src =
          Bt + (size_t)(f_ * 16 + r_) * NN + k0 + ch * 64 + kk_ * 32 + q_ * 8;
      gl_lds16(src, &lds[b][(size_t)(j * 512 + wave * 64) * 8]);
    }
  };

  vf4 acc0[8] = {}, acc1[8] = {};
  const float* a_base0 = adj + (size_t)(m0 + r) * NN + k0 + q * 8;
  const float* a_base1 = a_base0 + (size_t)16 * NN;

  stage(0, 0);
#pragma unroll 1
  for (int ch = 0; ch < CHUNKS; ++ch) {
    __syncthreads();                       // staging of lds[ch&1] complete
    if (ch + 1 < CHUNKS) stage(ch + 1, (ch + 1) & 1);
    const int b = ch & 1;
#pragma unroll
    for (int kk = 0; kk < 2; ++kk) {
      const int kc = ch * 64 + kk * 32;
      vf4 a00 = __builtin_nontemporal_load((const vf4*)(a_base0 + kc));
      vf4 a01 = __builtin_nontemporal_load((const vf4*)(a_base0 + kc) + 1);
      vf4 a10 = __builtin_nontemporal_load((const vf4*)(a_base1 + kc));
      vf4 a11 = __builtin_nontemporal_load((const vf4*)(a_base1 + kc) + 1);
      vbf8 af0 = frag_trunc(a00, a01);
      vbf8 af1 = frag_trunc(a10, a11);
#pragma unroll
      for (int f = 0; f < 8; ++f) {
        vbf8 bfr = *(const vbf8*)&lds[b][(size_t)(kk * 512 + f * 64 + lane) * 8];
        acc0[f] = __builtin_amdgcn_mfma_f32_16x16x32_bf16(af0, bfr, acc0[f], 0, 0, 0);
        acc1[f] = __builtin_amdgcn_mfma_f32_16x16x32_bf16(af1, bfr, acc1[f], 0, 0, 0);
      }
    }
  }

  // C/D: col n = f*16+r, row m = q*4+reg (+16 for acc1). Cpart[slice][n][m].
#pragma unroll
  for (int f = 0; f < 8; ++f) {
    short4 v0, v1;
    v0.x = (short)bf_rne(acc0[f][0]); v0.y = (short)bf_rne(acc0[f][1]);
    v0.z = (short)bf_rne(acc0[f][2]); v0.w = (short)bf_rne(acc0[f][3]);
    v1.x = (short)bf_rne(acc1[f][0]); v1.y = (short)bf_rne(acc1[f][1]);
    v1.z = (short)bf_rne(acc1[f][2]); v1.w = (short)bf_rne(acc1[f][3]);
    unsigned short* d0 = Cpart + ((size_t)slice * 128 + f * 16 + r) * NN + m0 + q * 4;
    *(short4*)d0 = v0;
    *(short4*)(d0 + 16) = v1;
  }
}

// ---------------- k3: csum[h] = sum_m PReLU(sum_s Cpart[s][h][m]+b[h])*msk[m]
__global__ __launch_bounds__(256) void k3_csum(
    const unsigned short* __restrict__ Cpart, const float* __restrict__ bias,
    const float* __restrict__ alpha_p, const float* __restrict__ msk,
    float* __restrict__ csum) {
  const int h = blockIdx.x >> 3, chunk = blockIdx.x & 7;  // 512 blocks
  const int t = threadIdx.x;
  const float alpha = alpha_p[0], b = bias[h];
  float sum = 0.f;
#pragma unroll
  for (int i = 0; i < 4; ++i) {
    const int m = chunk * 1024 + i * 256 + t;
    float v = 0.f;
#pragma unroll
    for (int s = 0; s < SPLIT; ++s)
      v += bf_to_f(Cpart[((size_t)s * 128 + h) * NN + m]);
    v += b;
    v = v > 0.f ? v : alpha * v;
    sum += v * msk[m];
  }
  __shared__ float red[256];
  red[t] = sum;
  __syncthreads();
  for (int off = 128; off > 32; off >>= 1) {
    if (t < off) red[t] += red[t + off];
    __syncthreads();
  }
  if (t < 32) {
    float v = red[t] + red[t + 32];
#pragma unroll
    for (int off = 16; off > 0; off >>= 1) v += __shfl_down(v, off, 64);
    if (t == 0) atomicAdd(&csum[h], v);
  }
}

// ---------------- k3b: msksum, c = sigmoid(csum/msksum), wc = disc_w @ c -----
__global__ __launch_bounds__(256) void k3b(
    const float* __restrict__ msk, const float* __restrict__ csum,
    const float* __restrict__ discw, float* __restrict__ wc) {
  const int t = threadIdx.x;
  __shared__ float red[256];
  __shared__ float c_sh[64];
  float ms = 0.f;
  for (int i = 0; i < 32; ++i) ms += msk[t + 256 * i];
  red[t] = ms;
  __syncthreads();
  for (int off = 128; off > 0; off >>= 1) {
    if (t < off) red[t] += red[t + off];
    __syncthreads();
  }
  if (t < 64) c_sh[t] = 1.f / (1.f + __expf(-csum[t] / red[0]));
  __syncthreads();
  if (t < 64) {
    float w = 0.f;
#pragma unroll
    for (int k = 0; k < 64; ++k) w += discw[t * 64 + k] * c_sh[k];
    wc[t] = w;
  }
}

// ---------------- k4: sc{1,2}[m] = sum_n PReLU(sum_s C[s][n][m]+b)*wc + db ----
__global__ __launch_bounds__(512) void k4_sc(
    const unsigned short* __restrict__ Cpart, const float* __restrict__ bias,
    const float* __restrict__ alpha_p, const float* __restrict__ wc,
    const float* __restrict__ discb, float* __restrict__ out) {
  const int t = threadIdx.x;
  const int ml = t & 63, g = t >> 6;        // 8 n-groups of 16
  const int m = blockIdx.x * 64 + ml;       // grid 128
  const float alpha = alpha_p[0];
  float sum = 0.f;
#pragma unroll
  for (int j = 0; j < 16; ++j) {
    const int n = g * 16 + j, h = n & 63;
    float v = 0.f;
#pragma unroll
    for (int s = 0; s < SPLIT; ++s)
      v += bf_to_f(Cpart[((size_t)s * 128 + n) * NN + m]);
    v += bias[h];
    v = v > 0.f ? v : alpha * v;
    sum += v * wc[h];
  }
  __shared__ float red[8][64];
  red[g][ml] = sum;
  __syncthreads();
  if (t < 128) {
    const int mm = t & 63, half = t >> 6;
    float r = red[half * 4 + 0][mm] + red[half * 4 + 1][mm] +
              red[half * 4 + 2][mm] + red[half * 4 + 3][mm];
    out[(size_t)half * NN + blockIdx.x * 64 + mm] = r + discb[0];
  }
}

extern "C" void kernel_launch(void* const* d_in, const int* in_sizes, int n_in,
                              void* d_out, int out_size, void* d_ws, size_t ws_size,
                              hipStream_t stream) {
  const float* seq1  = (const float*)d_in[0];
  const float* seq2  = (const float*)d_in[1];
  const float* adj   = (const float*)d_in[2];
  const float* msk   = (const float*)d_in[3];
  const float* fcw   = (const float*)d_in[4];
  const float* bias  = (const float*)d_in[5];
  const float* alpha = (const float*)d_in[6];
  const float* discw = (const float*)d_in[7];
  const float* discb = (const float*)d_in[8];
  float* out = (float*)d_out;
  char* ws = (char*)d_ws;

  unsigned short* Bt    = (unsigned short*)ws;                          // 2 MB
  unsigned short* Cpart = (unsigned short*)(ws + (size_t)(2 << 20));    // 32 MB
  float* csum           = (float*)(ws + (size_t)(34 << 20));            // 64 f
  float* wc             = csum + 64;                                    // 64 f

  hipLaunchKernelGGL(k1_fts, dim3(256), dim3(256), 0, stream, seq1, seq2, fcw, Bt, csum);
  hipLaunchKernelGGL(k2_agg, dim3(32 * SPLIT), dim3(512), 0, stream, adj, Bt, Cpart);
  hipLaunchKernelGGL(k3_csum, dim3(512), dim3(256), 0, stream, Cpart, bias, alpha, msk, csum);
  hipLaunchKernelGGL(k3b, dim3(1), dim3(256), 0, stream, msk, csum, discw, wc);
  hipLaunchKernelGGL(k4_sc, dim3(128), dim3(512), 0, stream, Cpart, bias, alpha, wc, discb, out);
}

// Round 4
// 412.523 us; speedup vs baseline: 1.2611x; 1.0203x over previous
//
#include <hip/hip_runtime.h>
#include <cstdint>
#include <cstddef>

#define NN 8192
#define FIN 256
#define HH 64
#define SPLIT 16
#define KLEN (NN / SPLIT)   // 512

typedef float vf4 __attribute__((ext_vector_type(4)));
typedef short vbf8 __attribute__((ext_vector_type(8)));

__device__ inline unsigned pk_trunc(float lo, float hi) {
  return __builtin_amdgcn_perm(__float_as_uint(hi), __float_as_uint(lo), 0x07060302u);
}
__device__ inline unsigned short bf_rne(float x) {
  unsigned u = __float_as_uint(x);
  return (unsigned short)((u + 0x7FFFu + ((u >> 16) & 1u)) >> 16);
}
__device__ inline float bf_to_f(unsigned short s) {
  return __uint_as_float(((unsigned)s) << 16);
}

union FragU { unsigned u[4]; unsigned short s[8]; vbf8 v; };

__device__ inline vbf8 frag_trunc(vf4 a, vf4 b) {
  FragU t;
  t.u[0] = pk_trunc(a[0], a[1]);
  t.u[1] = pk_trunc(a[2], a[3]);
  t.u[2] = pk_trunc(b[0], b[1]);
  t.u[3] = pk_trunc(b[2], b[3]);
  return t.v;
}
__device__ inline vbf8 frag_rne(vf4 a, vf4 b) {
  FragU t;
  t.s[0] = bf_rne(a[0]); t.s[1] = bf_rne(a[1]); t.s[2] = bf_rne(a[2]); t.s[3] = bf_rne(a[3]);
  t.s[4] = bf_rne(b[0]); t.s[5] = bf_rne(b[1]); t.s[6] = bf_rne(b[2]); t.s[7] = bf_rne(b[3]);
  return t.v;
}

__device__ inline void gl_lds16(const void* g, void* l) {
  __builtin_amdgcn_global_load_lds(
      (const __attribute__((address_space(1))) void*)g,
      (__attribute__((address_space(3))) void*)l, 16, 0, 0);
}

// ---------------- k1: fts = seq @ fc_w^T (both seqs), write Bt[n][k] bf16 -----
__global__ __launch_bounds__(256) void k1_fts(
    const float* __restrict__ seq1, const float* __restrict__ seq2,
    const float* __restrict__ fcw, unsigned short* __restrict__ Bt,
    float* __restrict__ csum) {
  const int bx = blockIdx.x;           // 256 blocks
  const int s = bx & 1, mb = bx >> 1;
  const int wave = threadIdx.x >> 6, lane = threadIdx.x & 63;
  const int r = lane & 15, q = lane >> 4;
  const int m0 = mb * 64 + wave * 16;
  if (bx == 0 && threadIdx.x < 64) csum[threadIdx.x] = 0.f;
  const float* seq = s ? seq2 : seq1;
  const float* ap = seq + (size_t)(m0 + r) * FIN + q * 8;
  const float* bp = fcw + (size_t)r * FIN + q * 8;
  vf4 acc[4] = {};
#pragma unroll
  for (int kk = 0; kk < FIN; kk += 32) {
    vf4 a0 = *(const vf4*)ap;
    vf4 a1 = *(const vf4*)(ap + 4);
    vbf8 af = frag_rne(a0, a1);
#pragma unroll
    for (int f = 0; f < 4; ++f) {
      vf4 b0 = *(const vf4*)(bp + (size_t)f * 16 * FIN);
      vf4 b1 = *(const vf4*)(bp + (size_t)f * 16 * FIN + 4);
      vbf8 bfr = frag_rne(b0, b1);
      acc[f] = __builtin_amdgcn_mfma_f32_16x16x32_bf16(af, bfr, acc[f], 0, 0, 0);
    }
    ap += 32; bp += 32;
  }
#pragma unroll
  for (int f = 0; f < 4; ++f) {
    short4 v;
    v.x = (short)bf_rne(acc[f][0]);
    v.y = (short)bf_rne(acc[f][1]);
    v.z = (short)bf_rne(acc[f][2]);
    v.w = (short)bf_rne(acc[f][3]);
    unsigned short* dst = Bt + (size_t)(64 * s + 16 * f + r) * NN + m0 + q * 4;
    *(short4*)dst = v;
  }
}

// ---------------- k2: Cpart[slice][n][m] = (adj[:,ks] @ B[ks,:])^T -----------
// Block: 512 thr = 8 waves, each wave 32 m-rows x 128 n. M_B=256.
// B slice staged to LDS in fragment order via global_load_lds w=16; K-chunk=128
// (2x32 KB double buffer, 64 KB LDS; 2 blocks/CU -> 128 KB < 160 KB, occupancy
// kept) -> only 4 barriers per kernel (each barrier costs a full vmcnt drain).
__global__ __launch_bounds__(512, 4) void k2_agg(
    const float* __restrict__ adj, const unsigned short* __restrict__ Bt,
    unsigned short* __restrict__ Cpart) {
  constexpr int CHUNKS = KLEN / 128;       // 4
  __shared__ unsigned short lds[2][16384]; // 2 x 32 KB
  const int bx = blockIdx.x;
  const int slice = bx & (SPLIT - 1), mb = bx / SPLIT;
  const int wave = threadIdx.x >> 6, lane = threadIdx.x & 63;
  const int r = lane & 15, q = lane >> 4;
  const int m0 = mb * 256 + wave * 32;
  const int k0 = slice * KLEN;

  // granule g (16 B) at lds offset g*16 holds Bt[f*16+r'][k0+ch*128+kk*32+q'*8]
  // with g = kk*512 + f*64 + q'*16 + r'; compute-side ds_read for frag (kk,f)
  // at granules (kk*512+f*64) + lane is then lane-contiguous, conflict-free.
  auto stage = [&](int ch, int b) {
#pragma unroll
    for (int j = 0; j < 4; ++j) {
      const int g = j * 512 + wave * 64 + lane;
      const int r_ = g & 15, q_ = (g >> 4) & 3, f_ = (g >> 6) & 7, kk_ = g >> 9;
      const unsigned short* src =
          Bt + (size_t)(f_ * 16 + r_) * NN + k0 + ch * 128 + kk_ * 32 + q_ * 8;
      gl_lds16(src, &lds[b][(size_t)(j * 512 + wave * 64) * 8]);
    }
  };

  vf4 acc0[8] = {}, acc1[8] = {};
  const float* a_base0 = adj + (size_t)(m0 + r) * NN + k0 + q * 8;
  const float* a_base1 = a_base0 + (size_t)16 * NN;

  stage(0, 0);
#pragma unroll 1
  for (int ch = 0; ch < CHUNKS; ++ch) {
    __syncthreads();                       // staging of lds[ch&1] complete
    if (ch + 1 < CHUNKS) stage(ch + 1, (ch + 1) & 1);
    const int b = ch & 1;
#pragma unroll
    for (int kk = 0; kk < 4; ++kk) {
      const int kc = ch * 128 + kk * 32;
      vf4 a00 = __builtin_nontemporal_load((const vf4*)(a_base0 + kc));
      vf4 a01 = __builtin_nontemporal_load((const vf4*)(a_base0 + kc) + 1);
      vf4 a10 = __builtin_nontemporal_load((const vf4*)(a_base1 + kc));
      vf4 a11 = __builtin_nontemporal_load((const vf4*)(a_base1 + kc) + 1);
      vbf8 af0 = frag_trunc(a00, a01);
      vbf8 af1 = frag_trunc(a10, a11);
#pragma unroll
      for (int f = 0; f < 8; ++f) {
        vbf8 bfr = *(const vbf8*)&lds[b][(size_t)(kk * 512 + f * 64 + lane) * 8];
        acc0[f] = __builtin_amdgcn_mfma_f32_16x16x32_bf16(af0, bfr, acc0[f], 0, 0, 0);
        acc1[f] = __builtin_amdgcn_mfma_f32_16x16x32_bf16(af1, bfr, acc1[f], 0, 0, 0);
      }
    }
  }

  // C/D: col n = f*16+r, row m = q*4+reg (+16 for acc1). Cpart[slice][n][m].
#pragma unroll
  for (int f = 0; f < 8; ++f) {
    short4 v0, v1;
    v0.x = (short)bf_rne(acc0[f][0]); v0.y = (short)bf_rne(acc0[f][1]);
    v0.z = (short)bf_rne(acc0[f][2]); v0.w = (short)bf_rne(acc0[f][3]);
    v1.x = (short)bf_rne(acc1[f][0]); v1.y = (short)bf_rne(acc1[f][1]);
    v1.z = (short)bf_rne(acc1[f][2]); v1.w = (short)bf_rne(acc1[f][3]);
    unsigned short* d0 = Cpart + ((size_t)slice * 128 + f * 16 + r) * NN + m0 + q * 4;
    *(short4*)d0 = v0;
    *(short4*)(d0 + 16) = v1;
  }
}

// ---------------- k3a: H[n][m] = PReLU(sum_s Cpart[s][n][m] + b) (bf16, 2 MB),
//                  csum[h] += sum_m H * msk  (for n < 64) ----------------------
__global__ __launch_bounds__(256) void k3a(
    const unsigned short* __restrict__ Cpart, const float* __restrict__ bias,
    const float* __restrict__ alpha_p, const float* __restrict__ msk,
    unsigned short* __restrict__ H, float* __restrict__ csum) {
  const int n = blockIdx.x >> 2, chunk = blockIdx.x & 3;  // 512 blocks
  const int t = threadIdx.x;
  const int m0 = chunk * 2048 + t * 8;
  const float alpha = alpha_p[0], b = bias[n & 63];
  float v[8] = {};
#pragma unroll
  for (int s = 0; s < SPLIT; ++s) {
    vbf8 c = *(const vbf8*)(Cpart + ((size_t)s * 128 + n) * NN + m0);
#pragma unroll
    for (int j = 0; j < 8; ++j) v[j] += bf_to_f((unsigned short)c[j]);
  }
  FragU hout;
  float acc = 0.f;
#pragma unroll
  for (int j = 0; j < 8; ++j) {
    float x = v[j] + b;
    x = x > 0.f ? x : alpha * x;
    hout.s[j] = bf_rne(x);
    acc += x * msk[m0 + j];
  }
  *(vbf8*)(H + (size_t)n * NN + m0) = hout.v;
  if (n < 64) {
    __shared__ float red[256];
    red[t] = acc;
    __syncthreads();
    for (int off = 128; off > 32; off >>= 1) {
      if (t < off) red[t] += red[t + off];
      __syncthreads();
    }
    if (t < 32) {
      float x = red[t] + red[t + 32];
#pragma unroll
      for (int off = 16; off > 0; off >>= 1) x += __shfl_down(x, off, 64);
      if (t == 0) atomicAdd(&csum[n], x);
    }
  }
}

// ---------------- k3b: msksum, c = sigmoid(csum/msksum), wc = disc_w @ c -----
__global__ __launch_bounds__(256) void k3b(
    const float* __restrict__ msk, const float* __restrict__ csum,
    const float* __restrict__ discw, float* __restrict__ wc) {
  const int t = threadIdx.x;
  __shared__ float red[256];
  __shared__ float c_sh[64];
  float ms = 0.f;
  for (int i = 0; i < 32; ++i) ms += msk[t + 256 * i];
  red[t] = ms;
  __syncthreads();
  for (int off = 128; off > 0; off >>= 1) {
    if (t < off) red[t] += red[t + off];
    __syncthreads();
  }
  if (t < 64) c_sh[t] = 1.f / (1.f + __expf(-csum[t] / red[0]));
  __syncthreads();
  if (t < 64) {
    float w = 0.f;
#pragma unroll
    for (int k = 0; k < 64; ++k) w += discw[t * 64 + k] * c_sh[k];
    wc[t] = w;
  }
}

// ---------------- k4: sc{1,2}[m] = sum_h H[(half*64+h)][m] * wc[h] + db ------
// H is 2 MB (L2/L3-resident); 128 blocks, wave w covers n = w*32..w*32+31.
__global__ __launch_bounds__(256) void k4_sc(
    const unsigned short* __restrict__ H, const float* __restrict__ wc,
    const float* __restrict__ discb, float* __restrict__ out) {
  const int t = threadIdx.x, lane = t & 63, w = t >> 6;
  const int m = blockIdx.x * 64 + lane;    // grid 128
  float s = 0.f;
#pragma unroll
  for (int i = 0; i < 32; ++i) {
    const int n = w * 32 + i;
    s += bf_to_f(H[(size_t)n * NN + m]) * wc[n & 63];
  }
  __shared__ float red[4][64];
  red[w][lane] = s;
  __syncthreads();
  if (t < 128) {
    const int half = t >> 6, mm = t & 63;
    out[(size_t)half * NN + blockIdx.x * 64 + mm] =
        red[half * 2][mm] + red[half * 2 + 1][mm] + discb[0];
  }
}

extern "C" void kernel_launch(void* const* d_in, const int* in_sizes, int n_in,
                              void* d_out, int out_size, void* d_ws, size_t ws_size,
                              hipStream_t stream) {
  const float* seq1  = (const float*)d_in[0];
  const float* seq2  = (const float*)d_in[1];
  const float* adj   = (const float*)d_in[2];
  const float* msk   = (const float*)d_in[3];
  const float* fcw   = (const float*)d_in[4];
  const float* bias  = (const float*)d_in[5];
  const float* alpha = (const float*)d_in[6];
  const float* discw = (const float*)d_in[7];
  const float* discb = (const float*)d_in[8];
  float* out = (float*)d_out;
  char* ws = (char*)d_ws;

  unsigned short* Bt    = (unsigned short*)ws;                          // 2 MB
  unsigned short* Cpart = (unsigned short*)(ws + (size_t)(2 << 20));    // 32 MB
  unsigned short* H     = (unsigned short*)(ws + (size_t)(34 << 20));   // 2 MB
  float* csum           = (float*)(ws + (size_t)(36 << 20));            // 64 f
  float* wc             = csum + 64;                                    // 64 f

  hipLaunchKernelGGL(k1_fts, dim3(256), dim3(256), 0, stream, seq1, seq2, fcw, Bt, csum);
  hipLaunchKernelGGL(k2_agg, dim3(32 * SPLIT), dim3(512), 0, stream, adj, Bt, Cpart);
  hipLaunchKernelGGL(k3a, dim3(512), dim3(256), 0, stream, Cpart, bias, alpha, msk, H, csum);
  hipLaunchKernelGGL(k3b, dim3(1), dim3(256), 0, stream, msk, csum, discw, wc);
  hipLaunchKernelGGL(k4_sc, dim3(128), dim3(256), 0, stream, H, wc, discb, out);
}